// Round 2
// baseline (105.488 us; speedup 1.0000x reference)
//
#include <hip/hip_runtime.h>
#include <hip/hip_bf16.h>

typedef __attribute__((ext_vector_type(4))) float f32x4;
typedef __attribute__((ext_vector_type(8))) short bf16x8;

#define M_TOT 30752   // 8*62*62 output pixels

__device__ __forceinline__ unsigned short f2bf(float f) {
  unsigned int u = __float_as_uint(f);
  u = u + 0x7FFF + ((u >> 16) & 1);   // round-to-nearest-even
  return (unsigned short)(u >> 16);
}

__device__ __forceinline__ void gload16(const void* g, void* l) {
  __builtin_amdgcn_global_load_lds((const __attribute__((address_space(1))) unsigned int*)g,
                                   (__attribute__((address_space(3))) unsigned int*)l,
                                   16, 0, 0);
}

// ---- prep 1: cast x (fp32) -> bf16, 8 elems/thread ----
__global__ void cast_x(const float* __restrict__ x, unsigned short* __restrict__ xb) {
  int i = blockIdx.x * 256 + threadIdx.x;
  const f32x4* xp = (const f32x4*)x;
  f32x4 a = xp[2 * i];
  f32x4 b = xp[2 * i + 1];
  bf16x8 o;
  o[0] = (short)f2bf(a[0]); o[1] = (short)f2bf(a[1]);
  o[2] = (short)f2bf(a[2]); o[3] = (short)f2bf(a[3]);
  o[4] = (short)f2bf(b[0]); o[5] = (short)f2bf(b[1]);
  o[6] = (short)f2bf(b[2]); o[7] = (short)f2bf(b[3]);
  ((bf16x8*)xb)[i] = o;
}

// ---- prep 2: K_eff[och][kk][f] = sum_bi Q[och,kk,bi] * S[16bi+(och>>4)][och&15][f]
__global__ void keff_k(const float* __restrict__ Q, const float* __restrict__ S,
                       float* __restrict__ Keff) {
  int bid = blockIdx.x;          // = och*9 + kk
  int o = bid / 9;
  int kk = bid - o * 9;
  int f = threadIdx.x;
  int qb = o * 144 + kk * 16;
  int sb = ((o >> 4) * 16 + (o & 15)) * 256 + f;
  float acc = 0.f;
#pragma unroll
  for (int bi = 0; bi < 16; ++bi)
    acc = fmaf(Q[qb + bi], S[sb + bi * 65536], acc);
  Keff[bid * 256 + f] = acc;
}

// ---- prep 3: K2t[kk][f][ci] = sum_o P[o][ci] * Keff[o][kk][f]  (bf16, transposed)
__global__ void k2t_k(const float* __restrict__ P, const float* __restrict__ Keff,
                      unsigned short* __restrict__ K2t) {
  int kk = blockIdx.x >> 4;
  int f0 = (blockIdx.x & 15) * 16;
  int ci = threadIdx.x;
  float acc[16];
#pragma unroll
  for (int j = 0; j < 16; ++j) acc[j] = 0.f;
  for (int o = 0; o < 256; ++o) {
    float pv = P[o * 256 + ci];
    const float* ke = Keff + (o * 9 + kk) * 256 + f0;
#pragma unroll
    for (int j = 0; j < 16; ++j) acc[j] = fmaf(pv, ke[j], acc[j]);
  }
#pragma unroll
  for (int j = 0; j < 16; ++j)
    K2t[kk * 65536 + (f0 + j) * 256 + ci] = f2bf(acc[j]);
}

// ---- main: implicit-GEMM conv.  M=30752, N=256, K=2304 (9 taps * 256 ch)
// BM=128, BN=128, BK=64. 256 threads (2x2 waves, 64x64/wave).
// Double-buffered 2-phase pipeline: stage(t+1) issued before compute(t),
// one barrier per K-step (barrier's vmcnt(0) drain lands ~350cy after issue).
__global__ __launch_bounds__(256) void conv_gemm(const unsigned short* __restrict__ xb,
                                                 const unsigned short* __restrict__ K2t,
                                                 float* __restrict__ out) {
  __shared__ unsigned short ldsA[2][128 * 64];   // 2 x 16KB, XOR-swizzled
  __shared__ unsigned short ldsB[2][128 * 64];   // 2 x 16KB, XOR-swizzled

  const int tid = threadIdx.x;
  const int lane = tid & 63;
  const int wid = tid >> 6;
  const int wm = wid >> 1;          // 0..1
  const int wn = wid & 1;           // 0..1
  const int bm = blockIdx.x >> 1;   // adjacent blocks share A-tile (L2 locality)
  const int bn = blockIdx.x & 1;
  const int m0 = bm * 128;

  // staging: thread t handles LDS chunks t+256q (row = rA+32q, slot = t&7).
  // T2 both-sides: source chunk slot = (t&7) ^ (row&7); row&7 == rA&7 (32q drops).
  const int swslot = ((tid & 7) ^ ((tid >> 3) & 7)) * 8;
  const int rA = tid >> 3;          // 0..31

  int gA[4];
#pragma unroll
  for (int q = 0; q < 4; ++q) {
    int m = m0 + rA + 32 * q; if (m >= M_TOT) m = M_TOT - 1;
    int b = m / 3844; int rem = m - b * 3844;
    int h = rem / 62; int w = rem - h * 62;
    gA[q] = ((b * 64 + h) * 64 + w) * 256 + swslot;
  }
  const int fB = bn * 128 + rA;     // B rows fB + 32q

  f32x4 zero = {0.f, 0.f, 0.f, 0.f};
  f32x4 acc[4][4];
#pragma unroll
  for (int i = 0; i < 4; ++i)
#pragma unroll
    for (int j = 0; j < 4; ++j) acc[i][j] = zero;

  const int rl = lane & 15;
  const int kg = lane >> 4;
  const int xm = (lane & 7) << 4;   // read-side XOR: (row&7)<<4, row&7 == lane&7

#define STAGE(t, buf)                                                          \
  {                                                                            \
    int kk_ = (t) >> 2, cb_ = (t) & 3;                                         \
    int kh_ = kk_ / 3, kw_ = kk_ - kh_ * 3;                                    \
    int offA_ = kh_ * 16384 + kw_ * 256 + cb_ * 64;                            \
    int offB_ = kk_ * 65536 + cb_ * 64 + swslot;                               \
    _Pragma("unroll")                                                          \
    for (int q = 0; q < 4; ++q)                                                \
      gload16(xb + gA[q] + offA_, &ldsA[buf][(tid + 256 * q) * 8]);            \
    _Pragma("unroll")                                                          \
    for (int q = 0; q < 4; ++q)                                                \
      gload16(K2t + offB_ + (fB + 32 * q) * 256, &ldsB[buf][(tid + 256 * q) * 8]); \
  }

  STAGE(0, 0);
  __syncthreads();

  for (int t = 0; t < 36; ++t) {
    int buf = t & 1;
    if (t < 35) STAGE(t + 1, buf ^ 1);

    bf16x8 af[4][2], bfr[4][2];
#pragma unroll
    for (int mi = 0; mi < 4; ++mi) {
      int rb = (wm * 64 + mi * 16 + rl) * 128;
#pragma unroll
      for (int ks = 0; ks < 2; ++ks) {
        int cbyte = (ks * 64 + kg * 16) ^ xm;
        af[mi][ks] = *(const bf16x8*)((const char*)ldsA[buf] + rb + cbyte);
      }
    }
#pragma unroll
    for (int ni = 0; ni < 4; ++ni) {
      int rb = (wn * 64 + ni * 16 + rl) * 128;
#pragma unroll
      for (int ks = 0; ks < 2; ++ks) {
        int cbyte = (ks * 64 + kg * 16) ^ xm;
        bfr[ni][ks] = *(const bf16x8*)((const char*)ldsB[buf] + rb + cbyte);
      }
    }
#pragma unroll
    for (int ks = 0; ks < 2; ++ks)
#pragma unroll
      for (int mi = 0; mi < 4; ++mi)
#pragma unroll
        for (int ni = 0; ni < 4; ++ni)
          acc[mi][ni] = __builtin_amdgcn_mfma_f32_16x16x32_bf16(
              af[mi][ks], bfr[ni][ks], acc[mi][ni], 0, 0, 0);

    __syncthreads();   // vmcnt(0) drain of STAGE(t+1) + protects buf for overwrite
  }

  // epilogue: D row = kg*4 + r (+16*mi +64*wm), col = rl (+16*ni +64*wn)
#pragma unroll
  for (int mi = 0; mi < 4; ++mi) {
    int mb = m0 + wm * 64 + mi * 16 + kg * 4;
#pragma unroll
    for (int ni = 0; ni < 4; ++ni) {
      int f = bn * 128 + wn * 64 + ni * 16 + rl;
#pragma unroll
      for (int r = 0; r < 4; ++r) {
        int m = mb + r;
        if (m < M_TOT) out[m * 256 + f] = acc[mi][ni][r];
      }
    }
  }
#undef STAGE
}

extern "C" void kernel_launch(void* const* d_in, const int* in_sizes, int n_in,
                              void* d_out, int out_size, void* d_ws, size_t ws_size,
                              hipStream_t stream) {
  const float* x = (const float*)d_in[0];   // [8,64,64,256]
  const float* P = (const float*)d_in[1];   // [256,256]
  const float* Q = (const float*)d_in[2];   // [256,3,3,16]
  const float* S = (const float*)d_in[3];   // [256,16,256]
  float* out = (float*)d_out;               // [8,62,62,256]

  char* ws = (char*)d_ws;
  unsigned short* xb   = (unsigned short*)ws;                        // 16,777,216 B
  float*          Keff = (float*)(ws + 16777216);                    //  2,359,296 B
  unsigned short* K2t  = (unsigned short*)(ws + 16777216 + 2359296); //  1,179,648 B

  cast_x<<<4096, 256, 0, stream>>>(x, xb);
  keff_k<<<2304, 256, 0, stream>>>(Q, S, Keff);
  k2t_k<<<144, 256, 0, stream>>>(P, Keff, K2t);
  conv_gemm<<<482, 256, 0, stream>>>(xb, K2t, out);
}